// Round 2
// baseline (1128.343 us; speedup 1.0000x reference)
//
#include <hip/hip_runtime.h>
#include <math.h>

#define W_IN     16384
#define FLT      32
#define W_OUT    (W_IN - FLT + 1)      // 16353
#define TILE_OUT 2048
#define TILE_IN  (TILE_OUT + FLT)      // 2080
#define R        8
#define NT       256
#define N_TILES  8                     // 8*2048 = 16384 >= 16353
#define LUT_N    2048
#define LUT_MAXM 16.0f                 // inputs are N(0,1); max mag ~6.2 << 16
#define LUT_SCL  (LUT_N / LUT_MAXM)    // 128.0f
#define OUT_SCALE 0.17782794100389228f // sqrt(10^(-15/10))

// LDS tile swizzle: logical 16B chunk c -> physical float index (c + c/8)*4.
// Inserts one pad chunk every 8 chunks: turns the 32B/lane-stride b128 read
// pattern (16-way bank alias) into 2-way (free per m136).
__device__ __forceinline__ int chunk_pf(int c) { return (c + (c >> 3)) << 2; }
#define PAD_CHUNKS (TILE_IN / 4 + TILE_IN / 32 + 1)   // 520 + 66

// ---- pre-kernel: build g(mag) = (sum_j c2_j * tanh(c1_j*mag)) / mag LUT ----
__global__ void build_lut_kernel(const float* __restrict__ w1,
                                 const float* __restrict__ w2,
                                 float* __restrict__ lut) {
    const int k = blockIdx.x * blockDim.x + threadIdx.x;
    if (k >= LUT_N) return;
    float c1[8], c2[8];
#pragma unroll
    for (int j = 0; j < 8; ++j) { c1[j] = w1[j]; c2[j] = w2[j]; }
    if (k == 0) {
        float g0 = 0.f;
#pragma unroll
        for (int j = 0; j < 8; ++j) g0 += c2[j] * c1[j];   // lim h(m)/m
        lut[0] = g0;
    } else {
        const float m = (float)k * (LUT_MAXM / LUT_N);
        float h = 0.f;
#pragma unroll
        for (int j = 0; j < 8; ++j) h += c2[j] * tanhf(c1[j] * m);
        lut[k] = h / m;
    }
}

__global__ __launch_bounds__(NT, 6)
void fused_env_mlp_fir_kernel(const float* __restrict__ xr,
                              const float* __restrict__ xi,
                              const float* __restrict__ lut_g,
                              const float* __restrict__ wlr,  // [32]
                              const float* __restrict__ wli,  // [32]
                              float* __restrict__ out)        // [1024, 16353, 2]
{
    __shared__ float slut[LUT_N];
    __shared__ float sxr[PAD_CHUNKS * 4];
    __shared__ float sxi[PAD_CHUNKS * 4];

    const int bid    = blockIdx.x;
    const int row    = bid >> 3;         // 0..1023
    const int tile   = bid & 7;          // 0..7
    const int tstart = tile * TILE_OUT;
    const int tid    = threadIdx.x;

    // ---- LUT: global -> LDS (2048 floats = 2 float4 per thread) ----
#pragma unroll
    for (int i = tid; i < LUT_N / 4; i += NT)
        *(float4*)(slut + i * 4) = *(const float4*)(lut_g + i * 4);
    __syncthreads();

    const float* __restrict__ xr_row = xr + (size_t)row * W_IN;
    const float* __restrict__ xi_row = xi + (size_t)row * W_IN;

    // ---- Stage 1: global -> envelope+MLP (LUT interp) -> LDS tiles ----
    for (int c = tid; c < TILE_IN / 4; c += NT) {      // 520 chunk tasks
        const int g = tstart + c * 4;
        float4 vr, vi;
        if (g + 3 < W_IN) {
            vr = *(const float4*)(xr_row + g);
            vi = *(const float4*)(xi_row + g);
        } else {
            vr = make_float4(0.f, 0.f, 0.f, 0.f);
            vi = make_float4(0.f, 0.f, 0.f, 0.f);
        }
        float ar[4] = {vr.x, vr.y, vr.z, vr.w};
        float ai[4] = {vi.x, vi.y, vi.z, vi.w};
        float orr[4], oii[4];
#pragma unroll
        for (int e = 0; e < 4; ++e) {
            const float a = ar[e], b = ai[e];
            const float s = fmaxf(fmaf(a, a, b * b), 1e-30f);
#if __has_builtin(__builtin_amdgcn_rsqf)
            const float rs = __builtin_amdgcn_rsqf(s);
#else
            const float rs = rsqrtf(s);
#endif
            const float mag  = s * rs;               // sqrt(s), fast
            const float idxf = mag * LUT_SCL;
            int i = (int)idxf;
            i = min(i, LUT_N - 2);
            const float fr = idxf - (float)i;
            const float g0 = slut[i], g1 = slut[i + 1];
            const float gg = fmaf(fr, g1 - g0, g0);  // h(mag)/mag
            orr[e] = a * gg;                         // h*cos(phase)
            oii[e] = b * gg;                         // h*sin(phase)
        }
        const int pf = chunk_pf(c);
        *(float4*)(sxr + pf) = make_float4(orr[0], orr[1], orr[2], orr[3]);
        *(float4*)(sxi + pf) = make_float4(oii[0], oii[1], oii[2], oii[3]);
    }
    __syncthreads();

    // ---- Stage 2: 32-tap complex FIR, R=8 outputs/thread, streaming window ----
    // window floats [8*tid, 8*tid+38] = chunks 2*tid .. 2*tid+9
    const int c0 = 2 * tid;
    float4 r0 = *(const float4*)(sxr + chunk_pf(c0 + 0));
    float4 i0 = *(const float4*)(sxi + chunk_pf(c0 + 0));
    float4 r1 = *(const float4*)(sxr + chunk_pf(c0 + 1));
    float4 i1 = *(const float4*)(sxi + chunk_pf(c0 + 1));
    float4 r2 = *(const float4*)(sxr + chunk_pf(c0 + 2));
    float4 i2 = *(const float4*)(sxi + chunk_pf(c0 + 2));

    float accr[R], acci[R];
#pragma unroll
    for (int r = 0; r < R; ++r) { accr[r] = 0.f; acci[r] = 0.f; }

#pragma unroll
    for (int g = 0; g < 8; ++g) {                    // taps 4g..4g+3
        const float wa[12] = {r0.x, r0.y, r0.z, r0.w, r1.x, r1.y, r1.z, r1.w,
                              r2.x, r2.y, r2.z, r2.w};
        const float wb[12] = {i0.x, i0.y, i0.z, i0.w, i1.x, i1.y, i1.z, i1.w,
                              i2.x, i2.y, i2.z, i2.w};
#pragma unroll
        for (int kk = 0; kk < 4; ++kk) {
            const int k = 4 * g + kk;
            const float wr = wlr[k];                 // uniform -> SGPR
            const float wi = wli[k];
#pragma unroll
            for (int r = 0; r < R; ++r) {
                const float a = wa[kk + r];
                const float b = wb[kk + r];
                accr[r] = fmaf(a,  wr, accr[r]);
                accr[r] = fmaf(b, -wi, accr[r]);
                acci[r] = fmaf(b,  wr, acci[r]);
                acci[r] = fmaf(a,  wi, acci[r]);
            }
        }
        r0 = r1; r1 = r2; i0 = i1; i1 = i2;
        if (g < 7) {
            r2 = *(const float4*)(sxr + chunk_pf(c0 + g + 3));
            i2 = *(const float4*)(sxi + chunk_pf(c0 + g + 3));
        }
    }

    float* __restrict__ out_row = out + (size_t)row * (W_OUT * 2);
    const int wbase = tstart + tid * R;
#pragma unroll
    for (int r = 0; r < R; ++r) {
        const int w = wbase + r;
        if (w < W_OUT) {
            *(float2*)(out_row + (size_t)w * 2) =
                make_float2(OUT_SCALE * accr[r], OUT_SCALE * acci[r]);
        }
    }
}

extern "C" void kernel_launch(void* const* d_in, const int* in_sizes, int n_in,
                              void* d_out, int out_size, void* d_ws, size_t ws_size,
                              hipStream_t stream) {
    const float* xr  = (const float*)d_in[0];
    const float* xi  = (const float*)d_in[1];
    const float* w1  = (const float*)d_in[2];
    const float* w2  = (const float*)d_in[3];
    const float* wlr = (const float*)d_in[4];
    const float* wli = (const float*)d_in[5];
    float* out = (float*)d_out;
    float* lut = (float*)d_ws;                       // 2048 floats, rebuilt every call

    build_lut_kernel<<<dim3(LUT_N / NT), dim3(NT), 0, stream>>>(w1, w2, lut);

    const int rows = 16 * 64;                        // B*H = 1024
    fused_env_mlp_fir_kernel<<<dim3(rows * N_TILES), dim3(NT), 0, stream>>>(
        xr, xi, lut, wlr, wli, out);
}

// Round 3
// 510.380 us; speedup vs baseline: 2.2108x; 2.2108x over previous
//
#include <hip/hip_runtime.h>
#include <math.h>

#define W_IN     16384
#define FLT      32
#define W_OUT    (W_IN - FLT + 1)      // 16353
#define TILE_OUT 2048
#define TILE_IN  (TILE_OUT + FLT)      // 2080
#define R        8
#define NT       256
#define N_TILES  8                     // 8*2048 = 16384 >= 16353
#define LUT_N    2048
#define LUT_MAXM 16.0f                 // inputs are N(0,1); max mag ~6.2 << 16
#define LUT_SCL  (LUT_N / LUT_MAXM)    // 128.0f
#define OUT_SCALE 0.17782794100389228f // sqrt(10^(-15/10))

// LDS tile swizzle: logical 16B chunk c -> physical float index (c + c/8)*4.
// Inserts one pad chunk every 8 chunks: turns the 32B/lane-stride b128 read
// pattern (16-way bank alias) into 2-way (free per m136).
__device__ __forceinline__ int chunk_pf(int c) { return (c + (c >> 3)) << 2; }
#define PAD_CHUNKS (TILE_IN / 4 + TILE_IN / 32 + 1)   // 520 + 66

// ---- pre-kernel: build g(mag) = (sum_j c2_j * tanh(c1_j*mag)) / mag LUT ----
__global__ void build_lut_kernel(const float* __restrict__ w1,
                                 const float* __restrict__ w2,
                                 float* __restrict__ lut) {
    const int k = blockIdx.x * blockDim.x + threadIdx.x;
    if (k >= LUT_N) return;
    float c1[8], c2[8];
#pragma unroll
    for (int j = 0; j < 8; ++j) { c1[j] = w1[j]; c2[j] = w2[j]; }
    if (k == 0) {
        float g0 = 0.f;
#pragma unroll
        for (int j = 0; j < 8; ++j) g0 += c2[j] * c1[j];   // lim h(m)/m
        lut[0] = g0;
    } else {
        const float m = (float)k * (LUT_MAXM / LUT_N);
        float h = 0.f;
#pragma unroll
        for (int j = 0; j < 8; ++j) h += c2[j] * tanhf(c1[j] * m);
        lut[k] = h / m;
    }
}

// launch_bounds note: (NT,6) in R2 capped VGPRs below the FIR live set and
// spilled ~3.4 GB to scratch (FETCH 2.35 GB). (NT,4) -> 128-VGPR cap, no spill;
// LDS (26.9 KB) limits to 5 blocks/CU anyway.
__global__ __launch_bounds__(NT, 4)
void fused_env_mlp_fir_kernel(const float* __restrict__ xr,
                              const float* __restrict__ xi,
                              const float* __restrict__ lut_g,
                              const float* __restrict__ wlr,  // [32]
                              const float* __restrict__ wli,  // [32]
                              float* __restrict__ out)        // [1024, 16353, 2]
{
    __shared__ float slut[LUT_N];
    __shared__ float sxr[PAD_CHUNKS * 4];
    __shared__ float sxi[PAD_CHUNKS * 4];

    const int bid    = blockIdx.x;
    const int row    = bid >> 3;         // 0..1023
    const int tile   = bid & 7;          // 0..7
    const int tstart = tile * TILE_OUT;
    const int tid    = threadIdx.x;

    // ---- LUT: global -> LDS (2048 floats = 2 float4 per thread) ----
#pragma unroll
    for (int i = tid; i < LUT_N / 4; i += NT)
        *(float4*)(slut + i * 4) = *(const float4*)(lut_g + i * 4);
    __syncthreads();

    const float* __restrict__ xr_row = xr + (size_t)row * W_IN;
    const float* __restrict__ xi_row = xi + (size_t)row * W_IN;

    // ---- Stage 1: global -> envelope+MLP (LUT interp) -> LDS tiles ----
    for (int c = tid; c < TILE_IN / 4; c += NT) {      // 520 chunk tasks
        const int g = tstart + c * 4;
        float4 vr, vi;
        if (g + 3 < W_IN) {
            vr = *(const float4*)(xr_row + g);
            vi = *(const float4*)(xi_row + g);
        } else {
            vr = make_float4(0.f, 0.f, 0.f, 0.f);
            vi = make_float4(0.f, 0.f, 0.f, 0.f);
        }
        float ar[4] = {vr.x, vr.y, vr.z, vr.w};
        float ai[4] = {vi.x, vi.y, vi.z, vi.w};
        float orr[4], oii[4];
#pragma unroll
        for (int e = 0; e < 4; ++e) {
            const float a = ar[e], b = ai[e];
            const float s = fmaxf(fmaf(a, a, b * b), 1e-30f);
#if __has_builtin(__builtin_amdgcn_rsqf)
            const float rs = __builtin_amdgcn_rsqf(s);
#else
            const float rs = rsqrtf(s);
#endif
            const float mag  = s * rs;               // sqrt(s), fast
            const float idxf = mag * LUT_SCL;
            int i = (int)idxf;
            i = min(i, LUT_N - 2);
            const float fr = idxf - (float)i;
            const float g0 = slut[i], g1 = slut[i + 1];
            const float gg = fmaf(fr, g1 - g0, g0);  // h(mag)/mag
            orr[e] = a * gg;                         // h*cos(phase)
            oii[e] = b * gg;                         // h*sin(phase)
        }
        const int pf = chunk_pf(c);
        *(float4*)(sxr + pf) = make_float4(orr[0], orr[1], orr[2], orr[3]);
        *(float4*)(sxi + pf) = make_float4(oii[0], oii[1], oii[2], oii[3]);
    }
    __syncthreads();

    // ---- Stage 2: 32-tap complex FIR, R=8 outputs/thread, streaming window ----
    // window floats [8*tid, 8*tid+38] = chunks 2*tid .. 2*tid+9
    const int c0 = 2 * tid;
    float4 r0 = *(const float4*)(sxr + chunk_pf(c0 + 0));
    float4 i0 = *(const float4*)(sxi + chunk_pf(c0 + 0));
    float4 r1 = *(const float4*)(sxr + chunk_pf(c0 + 1));
    float4 i1 = *(const float4*)(sxi + chunk_pf(c0 + 1));
    float4 r2 = *(const float4*)(sxr + chunk_pf(c0 + 2));
    float4 i2 = *(const float4*)(sxi + chunk_pf(c0 + 2));

    float accr[R], acci[R];
#pragma unroll
    for (int r = 0; r < R; ++r) { accr[r] = 0.f; acci[r] = 0.f; }

#pragma unroll
    for (int g = 0; g < 8; ++g) {                    // taps 4g..4g+3
        const float wa[12] = {r0.x, r0.y, r0.z, r0.w, r1.x, r1.y, r1.z, r1.w,
                              r2.x, r2.y, r2.z, r2.w};
        const float wb[12] = {i0.x, i0.y, i0.z, i0.w, i1.x, i1.y, i1.z, i1.w,
                              i2.x, i2.y, i2.z, i2.w};
#pragma unroll
        for (int kk = 0; kk < 4; ++kk) {
            const int k = 4 * g + kk;
            const float wr = wlr[k];                 // uniform -> SGPR
            const float wi = wli[k];
#pragma unroll
            for (int r = 0; r < R; ++r) {
                const float a = wa[kk + r];
                const float b = wb[kk + r];
                accr[r] = fmaf(a,  wr, accr[r]);
                accr[r] = fmaf(b, -wi, accr[r]);
                acci[r] = fmaf(b,  wr, acci[r]);
                acci[r] = fmaf(a,  wi, acci[r]);
            }
        }
        r0 = r1; r1 = r2; i0 = i1; i1 = i2;
        if (g < 7) {
            r2 = *(const float4*)(sxr + chunk_pf(c0 + g + 3));
            i2 = *(const float4*)(sxi + chunk_pf(c0 + g + 3));
        }
    }

    float* __restrict__ out_row = out + (size_t)row * (W_OUT * 2);
    const int wbase = tstart + tid * R;
#pragma unroll
    for (int r = 0; r < R; ++r) {
        const int w = wbase + r;
        if (w < W_OUT) {
            *(float2*)(out_row + (size_t)w * 2) =
                make_float2(OUT_SCALE * accr[r], OUT_SCALE * acci[r]);
        }
    }
}

extern "C" void kernel_launch(void* const* d_in, const int* in_sizes, int n_in,
                              void* d_out, int out_size, void* d_ws, size_t ws_size,
                              hipStream_t stream) {
    const float* xr  = (const float*)d_in[0];
    const float* xi  = (const float*)d_in[1];
    const float* w1  = (const float*)d_in[2];
    const float* w2  = (const float*)d_in[3];
    const float* wlr = (const float*)d_in[4];
    const float* wli = (const float*)d_in[5];
    float* out = (float*)d_out;
    float* lut = (float*)d_ws;                       // 2048 floats, rebuilt every call

    build_lut_kernel<<<dim3(LUT_N / NT), dim3(NT), 0, stream>>>(w1, w2, lut);

    const int rows = 16 * 64;                        // B*H = 1024
    fused_env_mlp_fir_kernel<<<dim3(rows * N_TILES), dim3(NT), 0, stream>>>(
        xr, xi, lut, wlr, wli, out);
}

// Round 4
// 252.175 us; speedup vs baseline: 4.4744x; 2.0239x over previous
//
#include <hip/hip_runtime.h>
#include <math.h>

#define W_IN     16384
#define FLT      32
#define W_OUT    (W_IN - FLT + 1)      // 16353
#define TILE_OUT 2048
#define TILE_IN  (TILE_OUT + FLT)      // 2080
#define R        8
#define NT       256
#define N_TILES  8                     // 8*2048 = 16384 >= 16353
#define LUT_N    2048
#define LUT_MAXM 16.0f                 // inputs are N(0,1); max mag ~6.2 << 16
#define LUT_SCL  (LUT_N / LUT_MAXM)    // 128.0f
#define OUT_SCALE 0.17782794100389228f // sqrt(10^(-15/10))

// LDS swizzle: logical 16B chunk c -> physical float index (c + c/8)*4.
// One pad chunk every 8 chunks; makes both the FIR window reads and the
// output-staging access patterns conflict-free (<=2-way, free per m136).
__device__ __forceinline__ int chunk_pf(int c) { return (c + (c >> 3)) << 2; }
#define PAD_CHUNKS (TILE_IN / 4 + TILE_IN / 32 + 1)   // 520 + 66 = 586
#define TILE_FLOATS (PAD_CHUNKS * 4)                   // 2344

// ---- pre-kernel: build g(mag) = (sum_j c2_j * tanh(c1_j*mag)) / mag LUT ----
__global__ void build_lut_kernel(const float* __restrict__ w1,
                                 const float* __restrict__ w2,
                                 float* __restrict__ lut) {
    const int k = blockIdx.x * blockDim.x + threadIdx.x;
    if (k >= LUT_N) return;
    float c1[8], c2[8];
#pragma unroll
    for (int j = 0; j < 8; ++j) { c1[j] = w1[j]; c2[j] = w2[j]; }
    if (k == 0) {
        float g0 = 0.f;
#pragma unroll
        for (int j = 0; j < 8; ++j) g0 += c2[j] * c1[j];   // lim h(m)/m
        lut[0] = g0;
    } else {
        const float m = (float)k * (LUT_MAXM / LUT_N);
        float h = 0.f;
#pragma unroll
        for (int j = 0; j < 8; ++j) h += c2[j] * tanhf(c1[j] * m);
        lut[k] = h / m;
    }
}

// (NT,6) spilled 3.4 GB (R2); (NT,4) -> 128-VGPR cap, measured 64 VGPR, no spill.
__global__ __launch_bounds__(NT, 4)
void fused_env_mlp_fir_kernel(const float* __restrict__ xr,
                              const float* __restrict__ xi,
                              const float* __restrict__ lut_g,
                              const float* __restrict__ wlr,  // [32]
                              const float* __restrict__ wli,  // [32]
                              float* __restrict__ out)        // [1024, 16353, 2]
{
    __shared__ float slut[LUT_N];
    __shared__ float stile[2 * TILE_FLOATS];   // sxr | sxi; reused for out staging
    float* const sxr = stile;
    float* const sxi = stile + TILE_FLOATS;

    const int bid    = blockIdx.x;
    const int row    = bid >> 3;         // 0..1023
    const int tile   = bid & 7;          // 0..7
    const int tstart = tile * TILE_OUT;
    const int tid    = threadIdx.x;

    // ---- LUT: global -> LDS ----
#pragma unroll
    for (int i = tid; i < LUT_N / 4; i += NT)
        *(float4*)(slut + i * 4) = *(const float4*)(lut_g + i * 4);
    __syncthreads();

    const float* __restrict__ xr_row = xr + (size_t)row * W_IN;
    const float* __restrict__ xi_row = xi + (size_t)row * W_IN;

    // ---- Stage 1: global -> envelope+MLP (LUT interp) -> LDS tiles ----
    for (int c = tid; c < TILE_IN / 4; c += NT) {      // 520 chunk tasks
        const int g = tstart + c * 4;
        float4 vr, vi;
        if (g + 3 < W_IN) {
            vr = *(const float4*)(xr_row + g);
            vi = *(const float4*)(xi_row + g);
        } else {
            vr = make_float4(0.f, 0.f, 0.f, 0.f);
            vi = make_float4(0.f, 0.f, 0.f, 0.f);
        }
        float ar[4] = {vr.x, vr.y, vr.z, vr.w};
        float ai[4] = {vi.x, vi.y, vi.z, vi.w};
        float orr[4], oii[4];
#pragma unroll
        for (int e = 0; e < 4; ++e) {
            const float a = ar[e], b = ai[e];
            const float s = fmaxf(fmaf(a, a, b * b), 1e-30f);
            const float rs = rsqrtf(s);
            const float mag  = s * rs;               // sqrt(s), fast
            const float idxf = mag * LUT_SCL;
            int i = (int)idxf;
            i = min(i, LUT_N - 2);
            const float fr = idxf - (float)i;
            const float g0 = slut[i], g1 = slut[i + 1];
            const float gg = fmaf(fr, g1 - g0, g0);  // h(mag)/mag
            orr[e] = a * gg;                         // h*cos(phase)
            oii[e] = b * gg;                         // h*sin(phase)
        }
        const int pf = chunk_pf(c);
        *(float4*)(sxr + pf) = make_float4(orr[0], orr[1], orr[2], orr[3]);
        *(float4*)(sxi + pf) = make_float4(oii[0], oii[1], oii[2], oii[3]);
    }
    __syncthreads();

    // ---- Stage 2: 32-tap complex FIR, R=8 outputs/thread, streaming window ----
    const int c0 = 2 * tid;
    float4 r0 = *(const float4*)(sxr + chunk_pf(c0 + 0));
    float4 i0 = *(const float4*)(sxi + chunk_pf(c0 + 0));
    float4 r1 = *(const float4*)(sxr + chunk_pf(c0 + 1));
    float4 i1 = *(const float4*)(sxi + chunk_pf(c0 + 1));
    float4 r2 = *(const float4*)(sxr + chunk_pf(c0 + 2));
    float4 i2 = *(const float4*)(sxi + chunk_pf(c0 + 2));

    float accr[R], acci[R];
#pragma unroll
    for (int r = 0; r < R; ++r) { accr[r] = 0.f; acci[r] = 0.f; }

#pragma unroll
    for (int g = 0; g < 8; ++g) {                    // taps 4g..4g+3
        const float wa[12] = {r0.x, r0.y, r0.z, r0.w, r1.x, r1.y, r1.z, r1.w,
                              r2.x, r2.y, r2.z, r2.w};
        const float wb[12] = {i0.x, i0.y, i0.z, i0.w, i1.x, i1.y, i1.z, i1.w,
                              i2.x, i2.y, i2.z, i2.w};
#pragma unroll
        for (int kk = 0; kk < 4; ++kk) {
            const int k = 4 * g + kk;
            const float wr = wlr[k];                 // uniform -> SGPR
            const float wi = wli[k];
#pragma unroll
            for (int r = 0; r < R; ++r) {
                const float a = wa[kk + r];
                const float b = wb[kk + r];
                accr[r] = fmaf(a,  wr, accr[r]);
                accr[r] = fmaf(b, -wi, accr[r]);
                acci[r] = fmaf(b,  wr, acci[r]);
                acci[r] = fmaf(a,  wi, acci[r]);
            }
        }
        r0 = r1; r1 = r2; i0 = i1; i1 = i2;
        if (g < 7) {
            r2 = *(const float4*)(sxr + chunk_pf(c0 + g + 3));
            i2 = *(const float4*)(sxi + chunk_pf(c0 + g + 3));
        }
    }

    // ---- Stage 3: stage interleaved (r,i) in LDS, then coalesced stores ----
    // R3 post-mortem: direct per-thread float2 stores at 64B lane stride gave
    // 6.4x HBM write amplification + RFO fetches. Round-trip through LDS so
    // each wave store instruction writes 512B contiguous.
    __syncthreads();                                  // all FIR reads done
    // thread t owns local outputs 8t..8t+7 -> 16 floats -> logical chunks 4t+j
#pragma unroll
    for (int j = 0; j < 4; ++j) {
        float4 v = make_float4(OUT_SCALE * accr[2 * j],
                               OUT_SCALE * acci[2 * j],
                               OUT_SCALE * accr[2 * j + 1],
                               OUT_SCALE * acci[2 * j + 1]);
        *(float4*)(stile + chunk_pf(4 * tid + j)) = v;
    }
    __syncthreads();

    float* __restrict__ out_row = out + (size_t)row * (W_OUT * 2);
    const int remain = W_OUT - tstart;                // valid local outputs
#pragma unroll
    for (int j = 0; j < 8; ++j) {                     // float2 unit u = local w
        const int u = tid + 256 * j;
        if (u < remain) {
            const float* p = stile + chunk_pf(u >> 1) + 2 * (u & 1);
            *(float2*)(out_row + (size_t)(tstart + u) * 2) =
                make_float2(p[0], p[1]);
        }
    }
}

extern "C" void kernel_launch(void* const* d_in, const int* in_sizes, int n_in,
                              void* d_out, int out_size, void* d_ws, size_t ws_size,
                              hipStream_t stream) {
    const float* xr  = (const float*)d_in[0];
    const float* xi  = (const float*)d_in[1];
    const float* w1  = (const float*)d_in[2];
    const float* w2  = (const float*)d_in[3];
    const float* wlr = (const float*)d_in[4];
    const float* wli = (const float*)d_in[5];
    float* out = (float*)d_out;
    float* lut = (float*)d_ws;                       // 2048 floats, rebuilt every call

    build_lut_kernel<<<dim3(LUT_N / NT), dim3(NT), 0, stream>>>(w1, w2, lut);

    const int rows = 16 * 64;                        // B*H = 1024
    fused_env_mlp_fir_kernel<<<dim3(rows * N_TILES), dim3(NT), 0, stream>>>(
        xr, xi, lut, wlr, wli, out);
}